// Round 6
// baseline (5925.115 us; speedup 1.0000x reference)
//
#include <hip/hip_runtime.h>
#include <hip/hip_bf16.h>

// Problem constants (from reference)
#define HH 512
#define WW 512
#define NN 8192
#define FF 2
#define BB 8
#define MM (NN * FF)      // 16384 splats per batch
#define HW (HH * WW)      // 262144 pixels per batch image

// Band decomposition: one 1024-thread block owns a 16-row x 512-col band in
// LDS (32 KB). 32 bands/batch x 8 batches = 256 blocks = 1 per CU.
#define BRLOG 4
#define BR 16                 // band rows
#define BANDS (HH / BR)       // 32 per image
#define NCH (MM / 64)         // 256 record-chunks per batch (64 records each)

// Native fp32 LDS atomic (ds_add_f32), fire-and-forget.
__device__ __forceinline__ void lds_add(float* p, float v) {
  unsafeAtomicAdd(p, v);
}

// readlane: wave-uniform (SGPR) or compile-time lane index.
__device__ __forceinline__ float readlane_f(float v, int l) {
  return __uint_as_float(__builtin_amdgcn_readlane(__float_as_uint(v), l));
}

// ---- dual-dtype input load: f32mode ? float : bf16 ----
__device__ __forceinline__ float ld(const void* p, int i, int f32mode) {
  if (f32mode) return ((const float*)p)[i];
  unsigned u = ((const unsigned short*)p)[i];
  return __uint_as_float(u << 16);
}

// Abramowitz & Stegun 7.1.26, |err| <= 1.5e-7. Saturates cleanly for |x|>~6
// (expf underflows to 0), so out-of-window lanes/rows self-mask (diff -> 0).
__device__ __forceinline__ float erf_f(float x) {
  float ax = fabsf(x);
  float t = 1.0f / (1.0f + 0.3275911f * ax);
  float y = t * (0.254829592f +
           t * (-0.284496736f +
           t * (1.421413741f +
           t * (-1.453152027f +
           t * 1.061405429f))));
  y = 1.0f - y * __expf(-ax * ax);
  return copysignf(y, x);
}

// K1: detect dtype, invert the 8 4x4 transforms (Gauss-Jordan), f32.
__global__ void k_inv(const void* __restrict__ T, float* __restrict__ invT,
                      int* __restrict__ flag) {
  int b = threadIdx.x;
  if (b >= BB) return;
  const float* Tf = (const float*)T;
  int f32mode = (fabsf(Tf[0] - 1.f) < 0.4f &&
                 fabsf(Tf[5] - 1.f) < 0.4f &&
                 fabsf(Tf[10] - 1.f) < 0.4f) ? 1 : 0;
  if (b == 0) *flag = f32mode;

  float a[4][8];
  for (int r = 0; r < 4; ++r)
    for (int c = 0; c < 4; ++c) {
      a[r][c] = ld(T, b * 16 + r * 4 + c, f32mode);
      a[r][4 + c] = (r == c) ? 1.0f : 0.0f;
    }
  for (int k = 0; k < 4; ++k) {
    int p = k; float best = fabsf(a[k][k]);
    for (int i = k + 1; i < 4; ++i) {
      float v = fabsf(a[i][k]);
      if (v > best) { best = v; p = i; }
    }
    if (p != k)
      for (int c = 0; c < 8; ++c) { float tmp = a[k][c]; a[k][c] = a[p][c]; a[p][c] = tmp; }
    float inv = 1.0f / a[k][k];
    for (int c = 0; c < 8; ++c) a[k][c] *= inv;
    for (int i = 0; i < 4; ++i) {
      if (i == k) continue;
      float f = a[i][k];
      for (int c = 0; c < 8; ++c) a[i][c] -= f * a[k][c];
    }
  }
  for (int r = 0; r < 4; ++r)
    for (int c = 0; c < 4; ++c)
      invT[b * 16 + r * 4 + c] = a[r][4 + c];
}

// K2: project records -> table {row, col, scale, weight}.
__global__ void __launch_bounds__(256)
k_proj(const void* __restrict__ centers, const void* __restrict__ scales,
       const void* __restrict__ weights, const float* __restrict__ invT,
       const int* __restrict__ flag, float4* __restrict__ table) {
  int idx = blockIdx.x * blockDim.x + threadIdx.x;   // exact cover [0, BB*MM)
  int f32mode = *flag;
  int b = idx >> 14;           // MM = 2^14
  int m = idx & (MM - 1);
  int n = m >> 1;              // FF = 2
  const float* Tb = invT + b * 16;
  float cx = ld(centers, 3 * n, f32mode);
  float cy = ld(centers, 3 * n + 1, f32mode);
  float cz = ld(centers, 3 * n + 2, f32mode);
  float p0 = Tb[0]  * cx + Tb[1]  * cy + Tb[2]  * cz + Tb[3];
  float p1 = Tb[4]  * cx + Tb[5]  * cy + Tb[6]  * cz + Tb[7];
  float p3 = Tb[12] * cx + Tb[13] * cy + Tb[14] * cz + Tb[15];
  float inv = 1.0f / p3;
  float4 rec;
  rec.x = p0 * inv;            // row (A2P = 1)
  rec.y = p1 * inv;            // col
  rec.z = ld(scales, m, f32mode);
  rec.w = ld(weights, m, f32mode);
  table[idx] = rec;
}

// K3: one block per (batch, 16-row band). Stream the batch's table with
// affine (non-dependent, prefetchable) loads; ballot-select records hitting
// the band; wave-cooperative erf splat into the LDS band via ds_add_f32.
// No lists, no global atomics, no cross-block dependencies.
__global__ void __launch_bounds__(1024)
k_band(const float4* __restrict__ table, const void* __restrict__ bwv,
       const int* __restrict__ flag, void* __restrict__ out) {
  __shared__ __align__(16) float tile[BR][WW];   // 32 KB
  int blk = blockIdx.x;
  int b = blk >> 5;                 // BANDS = 32
  int band = blk & (BANDS - 1);
  int row0 = band << BRLOG, row1 = row0 + BR - 1;
  int tid = threadIdx.x;
  int lane = tid & 63;
  int wv = tid >> 6;                // 16 waves
  int f32mode = *flag;

  for (int j = tid; j < BR * WW; j += 1024) ((float*)tile)[j] = 0.f;
  __syncthreads();

  const float4* tb = table + ((size_t)b << 14);
  float rowlane = (float)(row0 + lane) - 0.5f;   // lanes 0..16: row boundaries

  // wave wv scans chunks wv, wv+16, ... (16 chunks of 64 records each)
  int c = wv;
  float4 rec = tb[(c << 6) + lane];
  for (int it = 0; it < NCH / 16; ++it) {
    // prefetch next chunk (affine address, independent of current work)
    float4 nrec = rec;
    int cn = c + 16;
    if (cn < NCH) nrec = tb[(cn << 6) + lane];

    // ---- hit test: does this record touch rows [row0, row1]? ----
    float row = rec.x, s = rec.z;
    float Rf = 5.0f * s + 0.5f;
    int rlo = max(0, (int)ceilf(row - Rf));
    int rhi = min(HH - 1, (int)floorf(row + Rf));
    bool g = (rlo <= rhi) && (rlo <= row1) && (rhi >= row0);
    int myidx = (c << 6) + lane;
    bool bh = false;
    if ((myidx & 1) == 0) {
      int r0i = (int)floorf(row);
      int rr0 = min(max(r0i, 0), HH - 1), rr1 = min(max(r0i + 1, 0), HH - 1);
      bh = (rr0 <= row1) && (rr1 >= row0);
    }

    unsigned long long mask = __ballot(g || bh);
    while (mask) {
      int src = (int)__builtin_ctzll(mask);
      mask &= mask - 1;
      int i = (c << 6) + src;                       // record index within batch
      float prow = readlane_f(rec.x, src);
      float pcol = readlane_f(rec.y, src);
      float ps   = readlane_f(rec.z, src);
      float pwt  = readlane_f(rec.w, src);

      // ---- gaussian part (rows restricted to band; cols full window) ----
      float rs = 0.70710678118f / ps;               // 1/(s*sqrt(2))
      float Rf2 = 5.0f * ps + 0.5f;
      int grlo = max(0, (int)ceilf(prow - Rf2));
      int grhi = min(HH - 1, (int)floorf(prow + Rf2));
      int gclo = max(0, (int)ceilf(pcol - Rf2));
      int gchi = min(WW - 1, (int)floorf(pcol + Rf2));
      int srlo = max(grlo, row0), srhi = min(grhi, row1);
      if (srlo <= srhi && gclo <= gchi) {
        int nc = gchi - gclo + 1;
        float x = ((float)(gclo + lane) - 0.5f - pcol) * rs;
        float pq = (erf_f(x + rs) - erf_f(x)) * (0.25f * pwt);
        float Eh = erf_f((rowlane - prow) * rs);    // lanes 0..16 boundaries
        int k0 = srlo - row0, k1 = srhi - row0;
        float* trow = &tile[0][0] + (k0 << 9) + gclo + lane;
        for (int k = k0; k <= k1; ++k) {            // wave-uniform bounds
          float dh = readlane_f(Eh, k + 1) - readlane_f(Eh, k);
          if (lane < nc) lds_add(trow, dh * pq);
          trow += WW;
        }
      }

      // ---- bubble point-mass (f=0 records; lanes 0-3) ----
      if ((i & 1) == 0) {
        float r0f = floorf(prow), c0f = floorf(pcol);
        int r0i = (int)r0f, c0i = (int)c0f;
        int rr0 = min(max(r0i, 0), HH - 1), rr1 = min(max(r0i + 1, 0), HH - 1);
        if (rr0 <= row1 && rr1 >= row0) {
          float bw = ld(bwv, i >> 1, f32mode);
          float fr = prow - r0f, fc = pcol - c0f;
          int cc0 = min(max(c0i, 0), WW - 1), cc1 = min(max(c0i + 1, 0), WW - 1);
          int rsel = (lane < 2) ? rr0 : rr1;
          int csel = (lane & 1) ? cc1 : cc0;
          float wr = (lane < 2) ? (1.f - fr) : fr;
          float wc = (lane & 1) ? fc : (1.f - fc);
          if (lane < 4 && rsel >= row0 && rsel <= row1)
            lds_add(&tile[rsel - row0][csel], bw * wr * wc);
        }
      }
    }

    rec = nrec; c = cn;
  }
  __syncthreads();

  // ---- flush: band -> output (dtype per detected mode) ----
  size_t gbase = (size_t)b * HW + ((size_t)row0 << 9);
  const float4* t4 = (const float4*)tile;
  if (f32mode) {
    float4* o = (float4*)out + (gbase >> 2);
    for (int j = tid; j < BR * WW / 4; j += 1024) o[j] = t4[j];
  } else {
    ushort4* o = (ushort4*)out + (gbase >> 2);
    for (int j = tid; j < BR * WW / 4; j += 1024) {
      float4 v = t4[j];
      __hip_bfloat16 h0 = __float2bfloat16(v.x);
      __hip_bfloat16 h1 = __float2bfloat16(v.y);
      __hip_bfloat16 h2 = __float2bfloat16(v.z);
      __hip_bfloat16 h3 = __float2bfloat16(v.w);
      ushort4 t;
      t.x = *reinterpret_cast<unsigned short*>(&h0);
      t.y = *reinterpret_cast<unsigned short*>(&h1);
      t.z = *reinterpret_cast<unsigned short*>(&h2);
      t.w = *reinterpret_cast<unsigned short*>(&h3);
      o[j] = t;
    }
  }
}

extern "C" void kernel_launch(void* const* d_in, const int* in_sizes, int n_in,
                              void* d_out, int out_size, void* d_ws, size_t ws_size,
                              hipStream_t stream) {
  const void* T       = d_in[0];   // (B,4,4)
  const void* centers = d_in[1];   // (N,3)
  const void* scales  = d_in[2];   // (N,F)
  const void* weights = d_in[3];   // (N,F)
  const void* bubble  = d_in[4];   // (N,)

  char* ws = (char*)d_ws;
  size_t off = 0;
  float4* table = (float4*)(ws + off); off += (size_t)BB * MM * 16;   // 2 MB
  float*  invT  = (float*)(ws + off);  off += (size_t)BB * 16 * 4;    // 512 B
  int*    flag  = (int*)(ws + off);

  k_inv <<<1,             64,   0, stream>>>(T, invT, flag);
  k_proj<<<BB * MM / 256, 256,  0, stream>>>(centers, scales, weights, invT, flag, table);
  k_band<<<BB * BANDS,    1024, 0, stream>>>(table, bubble, flag, d_out);
}

// Round 7
// 731.369 us; speedup vs baseline: 8.1014x; 8.1014x over previous
//
#include <hip/hip_runtime.h>
#include <hip/hip_bf16.h>

// Problem constants (from reference)
#define HH 512
#define WW 512
#define NN 8192
#define FF 2
#define BB 8
#define MM (NN * FF)      // 16384 splats per batch
#define HW (HH * WW)      // 262144 pixels per batch image

// ---- dual-dtype input load: f32mode ? float : bf16 ----
__device__ __forceinline__ float ld(const void* p, int i, int f32mode) {
  if (f32mode) return ((const float*)p)[i];
  unsigned u = ((const unsigned short*)p)[i];
  return __uint_as_float(u << 16);
}

// readlane with wave-uniform index (SGPR) — no LDS traffic, no lgkm wait.
__device__ __forceinline__ float readlane_f(float v, int l) {
  return __uint_as_float(__builtin_amdgcn_readlane(__float_as_uint(v), l));
}

// Abramowitz & Stegun 7.1.26, |err| <= 1.5e-7.
__device__ __forceinline__ float erf_f(float x) {
  float ax = fabsf(x);
  float t = 1.0f / (1.0f + 0.3275911f * ax);
  float y = t * (0.254829592f +
           t * (-0.284496736f +
           t * (1.421413741f +
           t * (-1.453152027f +
           t * 1.061405429f))));
  y = 1.0f - y * __expf(-ax * ax);
  return copysignf(y, x);
}

// K1: detect dtype, then invert the 8 4x4 transforms (Gauss-Jordan), f32.
__global__ void k_inv(const void* __restrict__ T, float* __restrict__ invT,
                      int* __restrict__ flag) {
  int b = threadIdx.x;
  if (b >= BB) return;
  // dtype probe: under f32 data, words 0/5/10 are the diagonal of matrix 0 (≈1).
  const float* Tf = (const float*)T;
  int f32mode = (fabsf(Tf[0] - 1.f) < 0.4f &&
                 fabsf(Tf[5] - 1.f) < 0.4f &&
                 fabsf(Tf[10] - 1.f) < 0.4f) ? 1 : 0;
  if (b == 0) *flag = f32mode;

  float a[4][8];
  for (int r = 0; r < 4; ++r)
    for (int c = 0; c < 4; ++c) {
      a[r][c] = ld(T, b * 16 + r * 4 + c, f32mode);
      a[r][4 + c] = (r == c) ? 1.0f : 0.0f;
    }
  for (int k = 0; k < 4; ++k) {
    int p = k; float best = fabsf(a[k][k]);
    for (int i = k + 1; i < 4; ++i) {
      float v = fabsf(a[i][k]);
      if (v > best) { best = v; p = i; }
    }
    if (p != k)
      for (int c = 0; c < 8; ++c) { float tmp = a[k][c]; a[k][c] = a[p][c]; a[p][c] = tmp; }
    float inv = 1.0f / a[k][k];
    for (int c = 0; c < 8; ++c) a[k][c] *= inv;
    for (int i = 0; i < 4; ++i) {
      if (i == k) continue;
      float f = a[i][k];
      for (int c = 0; c < 8; ++c) a[i][c] -= f * a[k][c];
    }
  }
  for (int r = 0; r < 4; ++r)
    for (int c = 0; c < 4; ++c)
      invT[b * 16 + r * 4 + c] = a[r][4 + c];
}

// K2: build per-(b,m) splat records {row, col, scale, weight}; zero the f32 image.
__global__ void k_table(const void* __restrict__ centers, const void* __restrict__ scales,
                        const void* __restrict__ weights, const float* __restrict__ invT,
                        const int* __restrict__ flag,
                        float4* __restrict__ table, float4* __restrict__ img4) {
  int idx = blockIdx.x * blockDim.x + threadIdx.x;   // [0, BB*MM)
  int stride = gridDim.x * blockDim.x;
  for (int j = idx; j < BB * HW / 4; j += stride)
    img4[j] = make_float4(0.f, 0.f, 0.f, 0.f);
  if (idx >= BB * MM) return;
  int f32mode = *flag;
  int b = idx >> 14;           // MM = 2^14
  int m = idx & (MM - 1);
  int n = m >> 1;              // FF = 2
  const float* Tb = invT + b * 16;
  float cx = ld(centers, 3 * n, f32mode);
  float cy = ld(centers, 3 * n + 1, f32mode);
  float cz = ld(centers, 3 * n + 2, f32mode);
  float p0 = Tb[0]  * cx + Tb[1]  * cy + Tb[2]  * cz + Tb[3];
  float p1 = Tb[4]  * cx + Tb[5]  * cy + Tb[6]  * cz + Tb[7];
  float p3 = Tb[12] * cx + Tb[13] * cy + Tb[14] * cz + Tb[15];
  float inv = 1.0f / p3;
  float4 rec;
  rec.x = p0 * inv;            // row coordinate (A2P = 1)
  rec.y = p1 * inv;            // col coordinate
  rec.z = ld(scales, m, f32mode);
  rec.w = ld(weights, m, f32mode);
  table[idx] = rec;
}

// K3: wave-cooperative gaussian scatter, one wave per (b,m) splat, with the
// bilinear bubble point-mass folded into the f=0 splat's wave (lanes 0-3).
// Window truncated at 5*s (tail < 6e-7): width <= 42 <= 64 lanes.
// Atomics are NATIVE fire-and-forget global_atomic_add_f32 (unsafeAtomicAdd):
// the plain fp32 atomicAdd compiled to a CAS retry loop — the 2.2 GB
// FETCH_SIZE and 94%-idle waves of the round-0 profile.
__global__ void k_splat(const float4* __restrict__ table, const void* __restrict__ bwv,
                        const int* __restrict__ flag, float* __restrict__ img) {
  int gid = blockIdx.x * blockDim.x + threadIdx.x;
  int wave = gid >> 6;
  int lane = gid & 63;
  int nwaves = (gridDim.x * blockDim.x) >> 6;
  int f32mode = *flag;
  for (int i = wave; i < BB * MM; i += nwaves) {
    float4 rec = table[i];
    float row = rec.x, col = rec.y, s = rec.z, w = rec.w;
    float* imgb = img + ((i >> 14) << 18);   // b*HW

    // ---- bubble point-mass (f=0 records only; wave-uniform branch) ----
    if ((i & 1) == 0) {
      int n = (i & (MM - 1)) >> 1;
      float bw = ld(bwv, n, f32mode);
      float r0f = floorf(row), c0f = floorf(col);
      float fr = row - r0f, fc = col - c0f;
      int r0 = (int)r0f, c0 = (int)c0f;
      int rr0 = min(max(r0, 0), HH - 1), rr1 = min(max(r0 + 1, 0), HH - 1);
      int cc0 = min(max(c0, 0), WW - 1), cc1 = min(max(c0 + 1, 0), WW - 1);
      int rsel = (lane < 2) ? rr0 : rr1;
      int csel = (lane & 1) ? cc1 : cc0;
      float wr = (lane < 2) ? (1.f - fr) : fr;
      float wc = (lane & 1) ? fc : (1.f - fc);
      if (lane < 4)
        unsafeAtomicAdd(imgb + (rsel << 9) + csel, bw * wr * wc);
    }

    // ---- separable gaussian window scatter ----
    float rs = 0.70710678118f / s;           // 1/(s*sqrt(2))
    float Rf = 5.0f * s + 0.5f;
    int rlo = max(0, (int)ceilf(row - Rf));
    int rhi = min(HH - 1, (int)floorf(row + Rf));
    int clo = max(0, (int)ceilf(col - Rf));
    int chi = min(WW - 1, (int)floorf(col + Rf));
    if (rlo > rhi || clo > chi) continue;
    int nc = chi - clo + 1;
    int nr = rhi - rlo + 1;
    // column boundary erfs, lane l holds E at x = clo+l-0.5
    float Ew = erf_f(((float)(clo + lane) - 0.5f - col) * rs);
    // per-lane column profile, weight folded in: 0.25*w*(E[l+1]-E[l])
    float pwq = (__shfl_down(Ew, 1) - Ew) * (0.25f * w);
    // row boundary erfs and per-lane row deltas
    float Eh = erf_f(((float)(rlo + lane) - 0.5f - row) * rs);
    float Dh = __shfl_down(Eh, 1) - Eh;
    for (int k = 0; k < nr; ++k) {
      float dh = readlane_f(Dh, k);          // wave-uniform k: pure VALU, no lgkm
      if (lane < nc)
        unsafeAtomicAdd(imgb + ((rlo + k) << 9) + clo + lane, dh * pwq);
    }
  }
}

// K4: f32 -> output conversion (bf16 packed or f32 passthrough, per detected mode).
__global__ void k_final(const float4* __restrict__ img4, const int* __restrict__ flag,
                        void* __restrict__ out) {
  int idx = blockIdx.x * blockDim.x + threadIdx.x;
  int stride = gridDim.x * blockDim.x;
  int f32mode = *flag;
  if (f32mode) {
    float4* o = (float4*)out;
    for (int j = idx; j < BB * HW / 4; j += stride)
      o[j] = img4[j];
  } else {
    ushort4* o = (ushort4*)out;
    for (int j = idx; j < BB * HW / 4; j += stride) {
      float4 v = img4[j];
      __hip_bfloat16 h0 = __float2bfloat16(v.x);
      __hip_bfloat16 h1 = __float2bfloat16(v.y);
      __hip_bfloat16 h2 = __float2bfloat16(v.z);
      __hip_bfloat16 h3 = __float2bfloat16(v.w);
      ushort4 t;
      t.x = *reinterpret_cast<unsigned short*>(&h0);
      t.y = *reinterpret_cast<unsigned short*>(&h1);
      t.z = *reinterpret_cast<unsigned short*>(&h2);
      t.w = *reinterpret_cast<unsigned short*>(&h3);
      o[j] = t;
    }
  }
}

extern "C" void kernel_launch(void* const* d_in, const int* in_sizes, int n_in,
                              void* d_out, int out_size, void* d_ws, size_t ws_size,
                              hipStream_t stream) {
  const void* T       = d_in[0];   // (B,4,4)
  const void* centers = d_in[1];   // (N,3)
  const void* scales  = d_in[2];   // (N,F)
  const void* weights = d_in[3];   // (N,F)
  const void* bubble  = d_in[4];   // (N,)

  char* ws = (char*)d_ws;
  float*  img   = (float*)ws;                               // 8 MB f32 accumulator
  float4* table = (float4*)(ws + (size_t)BB * HW * 4);      // 2 MB splat records
  float*  invT  = (float*)(ws + (size_t)BB * HW * 4 + (size_t)BB * MM * 16); // 512 B
  int*    flag  = (int*)(invT + BB * 16);

  k_inv<<<1, 64, 0, stream>>>(T, invT, flag);
  k_table<<<512, 256, 0, stream>>>(centers, scales, weights, invT, flag, table, (float4*)img);
  k_splat<<<2048, 256, 0, stream>>>(table, bubble, flag, img);
  k_final<<<512, 256, 0, stream>>>((const float4*)img, flag, d_out);
}

// Round 8
// 606.184 us; speedup vs baseline: 9.7745x; 1.2065x over previous
//
#include <hip/hip_runtime.h>
#include <hip/hip_bf16.h>

// Problem constants (from reference)
#define HH 512
#define WW 512
#define NN 8192
#define FF 2
#define BB 8
#define MM (NN * FF)      // 16384 splats per batch
#define HW (HH * WW)      // 262144 pixels per batch image
#define NC (BB * NN)      // 65536 centers total

// ---- dual-dtype input load: f32mode ? float : bf16 ----
__device__ __forceinline__ float ld(const void* p, int i, int f32mode) {
  if (f32mode) return ((const float*)p)[i];
  unsigned u = ((const unsigned short*)p)[i];
  return __uint_as_float(u << 16);
}

// readlane with wave-uniform index (SGPR path) — pure VALU, no LDS traffic.
__device__ __forceinline__ float readlane_f(float v, int l) {
  return __uint_as_float(__builtin_amdgcn_readlane(__float_as_uint(v), l));
}

// Abramowitz & Stegun 7.1.26, |err| <= 1.5e-7.
__device__ __forceinline__ float erf_f(float x) {
  float ax = fabsf(x);
  float t = 1.0f / (1.0f + 0.3275911f * ax);
  float y = t * (0.254829592f +
           t * (-0.284496736f +
           t * (1.421413741f +
           t * (-1.453152027f +
           t * 1.061405429f))));
  y = 1.0f - y * __expf(-ax * ax);
  return copysignf(y, x);
}

// K1: detect dtype, then invert the 8 4x4 transforms (Gauss-Jordan), f32.
__global__ void k_inv(const void* __restrict__ T, float* __restrict__ invT,
                      int* __restrict__ flag) {
  int b = threadIdx.x;
  if (b >= BB) return;
  const float* Tf = (const float*)T;
  int f32mode = (fabsf(Tf[0] - 1.f) < 0.4f &&
                 fabsf(Tf[5] - 1.f) < 0.4f &&
                 fabsf(Tf[10] - 1.f) < 0.4f) ? 1 : 0;
  if (b == 0) *flag = f32mode;

  float a[4][8];
  for (int r = 0; r < 4; ++r)
    for (int c = 0; c < 4; ++c) {
      a[r][c] = ld(T, b * 16 + r * 4 + c, f32mode);
      a[r][4 + c] = (r == c) ? 1.0f : 0.0f;
    }
  for (int k = 0; k < 4; ++k) {
    int p = k; float best = fabsf(a[k][k]);
    for (int i = k + 1; i < 4; ++i) {
      float v = fabsf(a[i][k]);
      if (v > best) { best = v; p = i; }
    }
    if (p != k)
      for (int c = 0; c < 8; ++c) { float tmp = a[k][c]; a[k][c] = a[p][c]; a[p][c] = tmp; }
    float inv = 1.0f / a[k][k];
    for (int c = 0; c < 8; ++c) a[k][c] *= inv;
    for (int i = 0; i < 4; ++i) {
      if (i == k) continue;
      float f = a[i][k];
      for (int c = 0; c < 8; ++c) a[i][c] -= f * a[k][c];
    }
  }
  for (int r = 0; r < 4; ++r)
    for (int c = 0; c < 4; ++c)
      invT[b * 16 + r * 4 + c] = a[r][4 + c];
}

// K2: per-CENTER records (both features merged — same projected row/col):
// tabA[i] = {row, col, s0, w0}, tabB[i] = {s1, w1, bubble_w, 0}. Also zero img.
__global__ void k_table(const void* __restrict__ centers, const void* __restrict__ scales,
                        const void* __restrict__ weights, const void* __restrict__ bubble,
                        const float* __restrict__ invT, const int* __restrict__ flag,
                        float4* __restrict__ tabA, float4* __restrict__ tabB,
                        float4* __restrict__ img4) {
  int idx = blockIdx.x * blockDim.x + threadIdx.x;   // 512*256 = 131072 threads
  int stride = gridDim.x * blockDim.x;
  for (int j = idx; j < BB * HW / 4; j += stride)
    img4[j] = make_float4(0.f, 0.f, 0.f, 0.f);
  if (idx >= NC) return;
  int f32mode = *flag;
  int b = idx >> 13;           // NN = 2^13 centers per batch
  int n = idx & (NN - 1);
  const float* Tb = invT + b * 16;
  float cx = ld(centers, 3 * n, f32mode);
  float cy = ld(centers, 3 * n + 1, f32mode);
  float cz = ld(centers, 3 * n + 2, f32mode);
  float p0 = Tb[0]  * cx + Tb[1]  * cy + Tb[2]  * cz + Tb[3];
  float p1 = Tb[4]  * cx + Tb[5]  * cy + Tb[6]  * cz + Tb[7];
  float p3 = Tb[12] * cx + Tb[13] * cy + Tb[14] * cz + Tb[15];
  float inv = 1.0f / p3;
  float4 A, Bv;
  A.x = p0 * inv;              // row coordinate (A2P = 1)
  A.y = p1 * inv;              // col coordinate
  A.z = ld(scales, 2 * n, f32mode);       // s0
  A.w = ld(weights, 2 * n, f32mode);      // w0
  Bv.x = ld(scales, 2 * n + 1, f32mode);  // s1
  Bv.y = ld(weights, 2 * n + 1, f32mode); // w1
  Bv.z = ld(bubble, n, f32mode);          // bubble weight
  Bv.w = 0.f;
  tabA[idx] = A;
  tabB[idx] = Bv;
}

// K3: one wave per CENTER. Both features' separable-erf windows share the
// same (row,col), so each pixel gets ONE fused atomic: dh0*pw0 + dh1*pw1.
// Halves the memory-side atomic/write traffic vs per-splat scatter (the
// measured 363 GB/s HBM-write wall). Next-center records are prefetched
// BEFORE the atomic storm so the next load-use waits at vmcnt(N_atomics)
// instead of a full drain (vmcnt FIFO).
__global__ void k_splat(const float4* __restrict__ tabA, const float4* __restrict__ tabB,
                        float* __restrict__ img) {
  int gid = blockIdx.x * blockDim.x + threadIdx.x;
  int wave = gid >> 6;
  int lane = gid & 63;
  int nwaves = (gridDim.x * blockDim.x) >> 6;

  int i = wave;
  float4 A = make_float4(0.f, 0.f, 1.f, 0.f);
  float4 Bv = make_float4(1.f, 0.f, 0.f, 0.f);
  if (i < NC) { A = tabA[i]; Bv = tabB[i]; }

  while (i < NC) {
    // ---- prefetch next center (issued before the atomics: FIFO-friendly) --
    int in = i + nwaves;
    float4 An = A, Bn = Bv;
    if (in < NC) { An = tabA[in]; Bn = tabB[in]; }

    float row = A.x, col = A.y, s0 = A.z, w0 = A.w;
    float s1 = Bv.x, w1 = Bv.y, bw = Bv.z;
    float* imgb = img + ((size_t)(i >> 13) << 18);   // b*HW

    // ---- bubble point-mass (lanes 0-3) ----
    {
      float r0f = floorf(row), c0f = floorf(col);
      float fr = row - r0f, fc = col - c0f;
      int r0 = (int)r0f, c0 = (int)c0f;
      int rr0 = min(max(r0, 0), HH - 1), rr1 = min(max(r0 + 1, 0), HH - 1);
      int cc0 = min(max(c0, 0), WW - 1), cc1 = min(max(c0 + 1, 0), WW - 1);
      int rsel = (lane < 2) ? rr0 : rr1;
      int csel = (lane & 1) ? cc1 : cc0;
      float wr = (lane < 2) ? (1.f - fr) : fr;
      float wc = (lane & 1) ? fc : (1.f - fc);
      if (lane < 4)
        unsafeAtomicAdd(imgb + (rsel << 9) + csel, bw * wr * wc);
    }

    // ---- fused dual-feature separable gaussian over the union window ----
    float smax = fmaxf(s0, s1);
    float rs0 = 0.70710678118f / s0;         // 1/(s*sqrt(2))
    float rs1 = 0.70710678118f / s1;
    float Rf = 5.0f * smax + 0.5f;
    int rlo = max(0, (int)ceilf(row - Rf));
    int rhi = min(HH - 1, (int)floorf(row + Rf));
    int clo = max(0, (int)ceilf(col - Rf));
    int chi = min(WW - 1, (int)floorf(col + Rf));
    if (rlo <= rhi && clo <= chi) {
      int nc = chi - clo + 1;
      int nr = rhi - rlo + 1;
      // per-lane column profiles, weights folded (each lane: own 2 erfs)
      float xc = (float)(clo + lane) - 0.5f - col;
      float x0 = xc * rs0;
      float pw0 = (erf_f(x0 + rs0) - erf_f(x0)) * (0.25f * w0);
      float x1 = xc * rs1;
      float pw1 = (erf_f(x1 + rs1) - erf_f(x1)) * (0.25f * w1);
      // per-lane row deltas (lane k = row rlo+k), broadcast via readlane
      float yr = (float)(rlo + lane) - 0.5f - row;
      float y0 = yr * rs0;
      float Dh0 = erf_f(y0 + rs0) - erf_f(y0);
      float y1 = yr * rs1;
      float Dh1 = erf_f(y1 + rs1) - erf_f(y1);
      float* base = imgb + (rlo << 9) + clo + lane;
      for (int k = 0; k < nr; ++k) {
        float val = readlane_f(Dh0, k) * pw0 + readlane_f(Dh1, k) * pw1;
        if (lane < nc)
          unsafeAtomicAdd(base + (k << 9), val);
      }
    }

    i = in; A = An; Bv = Bn;
  }
}

// K4: f32 -> output conversion (bf16 packed or f32 passthrough, per detected mode).
__global__ void k_final(const float4* __restrict__ img4, const int* __restrict__ flag,
                        void* __restrict__ out) {
  int idx = blockIdx.x * blockDim.x + threadIdx.x;
  int stride = gridDim.x * blockDim.x;
  int f32mode = *flag;
  if (f32mode) {
    float4* o = (float4*)out;
    for (int j = idx; j < BB * HW / 4; j += stride)
      o[j] = img4[j];
  } else {
    ushort4* o = (ushort4*)out;
    for (int j = idx; j < BB * HW / 4; j += stride) {
      float4 v = img4[j];
      __hip_bfloat16 h0 = __float2bfloat16(v.x);
      __hip_bfloat16 h1 = __float2bfloat16(v.y);
      __hip_bfloat16 h2 = __float2bfloat16(v.z);
      __hip_bfloat16 h3 = __float2bfloat16(v.w);
      ushort4 t;
      t.x = *reinterpret_cast<unsigned short*>(&h0);
      t.y = *reinterpret_cast<unsigned short*>(&h1);
      t.z = *reinterpret_cast<unsigned short*>(&h2);
      t.w = *reinterpret_cast<unsigned short*>(&h3);
      o[j] = t;
    }
  }
}

extern "C" void kernel_launch(void* const* d_in, const int* in_sizes, int n_in,
                              void* d_out, int out_size, void* d_ws, size_t ws_size,
                              hipStream_t stream) {
  const void* T       = d_in[0];   // (B,4,4)
  const void* centers = d_in[1];   // (N,3)
  const void* scales  = d_in[2];   // (N,F)
  const void* weights = d_in[3];   // (N,F)
  const void* bubble  = d_in[4];   // (N,)

  char* ws = (char*)d_ws;
  size_t off = 0;
  float*  img  = (float*)(ws + off);  off += (size_t)BB * HW * 4;   // 8 MB
  float4* tabA = (float4*)(ws + off); off += (size_t)NC * 16;       // 1 MB
  float4* tabB = (float4*)(ws + off); off += (size_t)NC * 16;       // 1 MB
  float*  invT = (float*)(ws + off);  off += (size_t)BB * 16 * 4;   // 512 B
  int*    flag = (int*)(ws + off);

  k_inv<<<1, 64, 0, stream>>>(T, invT, flag);
  k_table<<<512, 256, 0, stream>>>(centers, scales, weights, bubble, invT, flag,
                                   tabA, tabB, (float4*)img);
  k_splat<<<2048, 256, 0, stream>>>(tabA, tabB, img);
  k_final<<<512, 256, 0, stream>>>((const float4*)img, flag, d_out);
}